// Round 4
// baseline (272.845 us; speedup 1.0000x reference)
//
#include <hip/hip_runtime.h>
#include <hip/hip_cooperative_groups.h>

namespace cg = cooperative_groups;

// Reduction: mean(|convdata[:,:,3] - output[:,:,3]|)
// B=64, S=100, K=4, H=W=32. Channel-3 slice per (b,s) pair is a contiguous
// 1024-float (4 KB) chunk at float offset (pair*4 + 3)*1024.
// Total reduced: 64*100*1024 = 6,553,600 elems (52.4 MB read).
//
// Round-3 counters: harness poison fill (419 MB, 61 us, BW-bound) is inside
// the timed window; our kernels are each <60 us; removing one graph node
// (round 0->1 A/B) was worth ~20 us. So: minimize OUR dispatch count to ONE
// via cooperative launch (grid sync between partial phase and final reduce).
// No memset anywhere; out[0] is overwritten.
//
// Grid: 1024 blocks x 256 thr = 4096 waves (co-residency safe for coop;
// low VGPR). Each block owns whole 4KB chunks (256 float4 <-> 256 threads).

#define RBLOCKS 1024
#define RTHREADS 256
#define NCHUNKS 6400   // 64*100 (b,s) pairs, one 4KB channel-3 chunk each

__global__ __launch_bounds__(RTHREADS)
void absdiff_coop_kernel(const float4* __restrict__ outp,
                         const float4* __restrict__ conv,
                         float* __restrict__ partials,
                         float* __restrict__ out,
                         float inv_total) {
    const int t = threadIdx.x;
    float acc0 = 0.0f, acc1 = 0.0f;

    // Block b handles chunks b, b+1024, ..., pairwise-unrolled.
    // blocks 0..255 get 7 chunks, the rest 6 (6*1024 + 256 = 6400).
    int c = blockIdx.x;
    for (; c + RBLOCKS < NCHUNKS; c += 2 * RBLOCKS) {
        const size_t g0 = (size_t)c * 1024 + 768 + t;
        const size_t g1 = (size_t)(c + RBLOCKS) * 1024 + 768 + t;
        const float4 a0 = outp[g0];
        const float4 b0 = conv[g0];
        const float4 a1 = outp[g1];
        const float4 b1 = conv[g1];
        acc0 += fabsf(b0.x - a0.x) + fabsf(b0.y - a0.y)
              + fabsf(b0.z - a0.z) + fabsf(b0.w - a0.w);
        acc1 += fabsf(b1.x - a1.x) + fabsf(b1.y - a1.y)
              + fabsf(b1.z - a1.z) + fabsf(b1.w - a1.w);
    }
    if (c < NCHUNKS) {
        const size_t g = (size_t)c * 1024 + 768 + t;
        const float4 a = outp[g];
        const float4 b = conv[g];
        acc0 += fabsf(b.x - a.x) + fabsf(b.y - a.y)
              + fabsf(b.z - a.z) + fabsf(b.w - a.w);
    }
    float acc = acc0 + acc1;

    // wave-64 shuffle reduction
    #pragma unroll
    for (int off = 32; off > 0; off >>= 1)
        acc += __shfl_down(acc, off, 64);

    __shared__ float smem[RTHREADS / 64];
    const int lane = t & 63;
    const int wave = t >> 6;
    if (lane == 0) smem[wave] = acc;
    __syncthreads();
    if (t == 0) {
        float s = 0.0f;
        #pragma unroll
        for (int w = 0; w < RTHREADS / 64; ++w) s += smem[w];
        partials[blockIdx.x] = s;
    }

    // Grid-wide barrier (device-scope fence included), then block 0 finishes.
    cg::this_grid().sync();

    if (blockIdx.x == 0) {
        float a = partials[t] + partials[t + 256]
                + partials[t + 512] + partials[t + 768];
        #pragma unroll
        for (int off = 32; off > 0; off >>= 1)
            a += __shfl_down(a, off, 64);
        if (lane == 0) smem[wave] = a;
        __syncthreads();
        if (t == 0) {
            float s = 0.0f;
            #pragma unroll
            for (int w = 0; w < RTHREADS / 64; ++w) s += smem[w];
            out[0] = s * inv_total;   // overwrite — no zero-init needed
        }
    }
}

extern "C" void kernel_launch(void* const* d_in, const int* in_sizes, int n_in,
                              void* d_out, int out_size, void* d_ws, size_t ws_size,
                              hipStream_t stream) {
    const float4* outp = (const float4*)d_in[0];   // "output"
    const float4* conv = (const float4*)d_in[1];   // "convdata"
    float* partials = (float*)d_ws;                // RBLOCKS floats (4 KB)
    float* out = (float*)d_out;
    float inv_total = 1.0f / (float)(64 * 100 * 1024);

    void* args[] = {(void*)&outp, (void*)&conv, (void*)&partials,
                    (void*)&out, (void*)&inv_total};
    hipLaunchCooperativeKernel((const void*)absdiff_coop_kernel,
                               dim3(RBLOCKS), dim3(RTHREADS),
                               args, 0, stream);
}

// Round 6
// 181.840 us; speedup vs baseline: 1.5005x; 1.5005x over previous
//
#include <hip/hip_runtime.h>

// Reduction: mean(|convdata[:,:,3] - output[:,:,3]|)
// B=64, S=100, K=4, H=W=32. Channel-3 slice per (b,s) pair is a contiguous
// 1024-float (4 KB) chunk at float offset (pair*4 + 3)*1024.
// Total reduced: 64*100*1024 = 6,553,600 elems (52.4 MB read; ~half is
// L2/L3-resident right after the harness poison fill, per round-4 counters).
//
// Round-4 lesson: cooperative grid-sync costs ~85 us at 1024 blocks — far
// more than a kernel node. Best structure remains TWO plain dispatches,
// no memset (fillBuffer graph nodes cost ~20+ us, round-0/1 A/B).
//
// This round: partial kernel with ZERO loop — 6400 blocks, one 4 KB chunk
// per block, one float4 pair-read per thread. Max TLP (25,600 waves),
// minimal address math, blocks retire immediately.

#define RTHREADS 256
#define NCHUNKS 6400   // 64*100 (b,s) pairs, one 4KB channel-3 chunk each

__global__ __launch_bounds__(RTHREADS)
void absdiff_partial_kernel(const float4* __restrict__ outp,
                            const float4* __restrict__ conv,
                            float* __restrict__ partials) {
    const int t = threadIdx.x;
    // Chunk = blockIdx.x; channel-3 data at float4 index chunk*1024 + 768 + t.
    const size_t g = (size_t)blockIdx.x * 1024 + 768 + t;
    const float4 a = outp[g];
    const float4 b = conv[g];
    float acc = fabsf(b.x - a.x) + fabsf(b.y - a.y)
              + fabsf(b.z - a.z) + fabsf(b.w - a.w);

    // wave-64 shuffle reduction
    #pragma unroll
    for (int off = 32; off > 0; off >>= 1)
        acc += __shfl_down(acc, off, 64);

    __shared__ float smem[RTHREADS / 64];
    const int lane = t & 63;
    const int wave = t >> 6;
    if (lane == 0) smem[wave] = acc;
    __syncthreads();
    if (t == 0) {
        float s = 0.0f;
        #pragma unroll
        for (int w = 0; w < RTHREADS / 64; ++w) s += smem[w];
        partials[blockIdx.x] = s;
    }
}

__global__ __launch_bounds__(RTHREADS)
void final_reduce_kernel(const float* __restrict__ partials,
                         float* __restrict__ out, float inv_total) {
    float acc = 0.0f;
    // 6400 partials / 256 threads = 25 each.
    #pragma unroll
    for (int i = 0; i < NCHUNKS / RTHREADS; ++i)
        acc += partials[threadIdx.x + i * RTHREADS];
    #pragma unroll
    for (int off = 32; off > 0; off >>= 1)
        acc += __shfl_down(acc, off, 64);
    __shared__ float smem[RTHREADS / 64];
    const int lane = threadIdx.x & 63;
    const int wave = threadIdx.x >> 6;
    if (lane == 0) smem[wave] = acc;
    __syncthreads();
    if (threadIdx.x == 0) {
        float s = 0.0f;
        #pragma unroll
        for (int w = 0; w < RTHREADS / 64; ++w) s += smem[w];
        out[0] = s * inv_total;   // overwrite — no zero-init needed
    }
}

extern "C" void kernel_launch(void* const* d_in, const int* in_sizes, int n_in,
                              void* d_out, int out_size, void* d_ws, size_t ws_size,
                              hipStream_t stream) {
    const float4* outp = (const float4*)d_in[0];   // "output"
    const float4* conv = (const float4*)d_in[1];   // "convdata"
    float* partials = (float*)d_ws;                // NCHUNKS floats (25.6 KB)
    float* out = (float*)d_out;

    const float inv_total = 1.0f / (float)(64 * 100 * 1024);

    absdiff_partial_kernel<<<NCHUNKS, RTHREADS, 0, stream>>>(outp, conv, partials);
    final_reduce_kernel<<<1, RTHREADS, 0, stream>>>(partials, out, inv_total);
}